// Round 1
// 950.675 us; speedup vs baseline: 1.1107x; 1.1107x over previous
//
#include <hip/hip_runtime.h>
#include <cstdint>

// Problem constants
#define KH   4      // n_codebooks (heads)
#define DM   1024   // d_model
#define HID  2048   // hidden
#define RP   1024   // repr
#define VOC  2052   // vocab
#define VPAD 2304   // vocab padded to multiple of 256 (tile_n)
#define TT   2048   // T
#define MM   8192   // B*T tokens

typedef short bf16x8 __attribute__((ext_vector_type(8)));
typedef float f32x4  __attribute__((ext_vector_type(4)));

__device__ __forceinline__ unsigned short f2bf(float f) {
  union { float f; unsigned int u; } a; a.f = f;
  unsigned int u = a.u;
  unsigned int r = (u + 0x7fffu + ((u >> 16) & 1u)) >> 16;  // RNE
  return (unsigned short)r;
}

// Fast exact-ish GELU: tanh form via hw exp+rcp. |err vs erf-GELU| < ~5e-4.
__device__ __forceinline__ float fast_gelu(float v) {
  float u = v * (0.7978845608028654f + 0.035677408136300125f * v * v);
  float e = __expf(2.0f * u);
  float r = __builtin_amdgcn_rcpf(e + 1.0f);
  return v - v * r;
}

// global -> LDS direct copy, 16B per lane. LDS dst must be wave-uniform base;
// HW writes lane i's 16B to (base + i*16). Global src is per-lane.
__device__ __forceinline__ void async_cp16(const unsigned short* g, unsigned short* l) {
  __builtin_amdgcn_global_load_lds(
      (const __attribute__((address_space(1))) unsigned int*)(uintptr_t)g,
      (__attribute__((address_space(3))) unsigned int*)(uintptr_t)l,
      16, 0, 0);
}

// ---------------------------------------------------------------------------
// LayerNorm stats (per token) -> xn bf16 [MM][DM]
// ---------------------------------------------------------------------------
__global__ __launch_bounds__(256) void ln_kernel(const float* __restrict__ x,
                                                 unsigned short* __restrict__ xn) {
  int row = blockIdx.x;
  int tid = threadIdx.x;
  const float4* xr = (const float4*)(x + (size_t)row * DM);
  float4 v = xr[tid];
  float s  = v.x + v.y + v.z + v.w;
  float s2 = v.x * v.x + v.y * v.y + v.z * v.z + v.w * v.w;
  for (int o = 32; o > 0; o >>= 1) {
    s  += __shfl_down(s, o);
    s2 += __shfl_down(s2, o);
  }
  __shared__ float ps[8];
  int wave = tid >> 6, lane = tid & 63;
  if (lane == 0) { ps[wave] = s; ps[wave + 4] = s2; }
  __syncthreads();
  if (tid == 0) {
    float ts  = ps[0] + ps[1] + ps[2] + ps[3];
    float ts2 = ps[4] + ps[5] + ps[6] + ps[7];
    float mean = ts * (1.0f / DM);
    float var  = ts2 * (1.0f / DM) - mean * mean;
    ps[0] = mean;
    ps[1] = rsqrtf(var + 1e-5f);
  }
  __syncthreads();
  float mean = ps[0], rstd = ps[1];
  ushort4 o4;
  o4.x = f2bf((v.x - mean) * rstd);
  o4.y = f2bf((v.y - mean) * rstd);
  o4.z = f2bf((v.z - mean) * rstd);
  o4.w = f2bf((v.w - mean) * rstd);
  ((ushort4*)(xn + (size_t)row * DM))[tid] = o4;
}

// ---------------------------------------------------------------------------
// b1s[k][h] = b1[k][h] + sum_d ln_bias[k][d] * W1[k][d][h]   (fp32)
// ---------------------------------------------------------------------------
__global__ __launch_bounds__(256) void fold_b1(const float* __restrict__ W1,
                                               const float* __restrict__ b1,
                                               const float* __restrict__ ln_bias,
                                               float* __restrict__ b1s) {
  int k  = blockIdx.y;
  int h0 = blockIdx.x * 64;
  int hl = threadIdx.x & 63;
  int dg = threadIdx.x >> 6;
  const float* Wk = W1 + (size_t)k * DM * HID;
  const float* lb = ln_bias + (size_t)k * DM;
  float acc = 0.f;
  for (int d = dg * 256; d < dg * 256 + 256; ++d)
    acc += lb[d] * Wk[(size_t)d * HID + h0 + hl];
  __shared__ float red[4][64];
  red[dg][hl] = acc;
  __syncthreads();
  if (dg == 0)
    b1s[(size_t)k * HID + h0 + hl] =
        b1[(size_t)k * HID + h0 + hl] + red[0][hl] + red[1][hl] + red[2][hl] + red[3][hl];
}

// ---------------------------------------------------------------------------
// Transpose + fp32->bf16 convert (+ optional per-src-row scale)
// src [k][Rr][Cc] fp32 -> dst [k][Cpad][Rr] bf16; zero-fills c in [Cc, Cpad)
// ---------------------------------------------------------------------------
__global__ __launch_bounds__(256) void transpose_conv(const float* __restrict__ src,
                                                      unsigned short* __restrict__ dst,
                                                      const float* __restrict__ scale,
                                                      int Rr, int Cc, int Cpad,
                                                      int dstHeadStride) {
  int k  = blockIdx.z;
  int c0 = blockIdx.x * 32, r0 = blockIdx.y * 32;
  int tx = threadIdx.x & 31, ty = threadIdx.x >> 5;
  __shared__ float tile[32][33];
  const float* s = src + (size_t)k * Rr * Cc;
  for (int q = 0; q < 4; q++) {
    int r = r0 + ty + q * 8;
    int c = c0 + tx;
    float v = 0.f;
    if (c < Cc) v = s[(size_t)r * Cc + c];
    if (scale) v *= scale[(size_t)k * Rr + r];
    tile[ty + q * 8][tx] = v;
  }
  __syncthreads();
  unsigned short* d = dst + (size_t)k * dstHeadStride;
  for (int q = 0; q < 4; q++) {
    int c = c0 + ty + q * 8;
    int r = r0 + tx;
    if (c < Cpad) d[(size_t)c * Rr + r] = f2bf(tile[tx][ty + q * 8]);
  }
}

// ---------------------------------------------------------------------------
// Grouped 256x256 8-phase gemm_bt (counted-vmcnt template, T1+T3+T4+T5).
//   C[M][N] = A[M][Kd] @ Bt[N][Kd]^T + bias, fused epilogue per MODE.
// 512 threads = 8 waves (2M x 4N); per-wave output 128x64; BK=64.
// LDS: per K-tile, A and B each split into TWO K-halves [256 rows][32 k]
// (16 KB each). This layout makes global_load_lds dests linear AND every
// ds_read_b128 frag read cover a contiguous 1024B span -> conflict-free,
// no swizzle needed on either side.
// Staging order per tile t (issued during tile t-1, 1 half per phase):
//   A-K0, B-K0, A-K1, B-K1  -> every wait is vmcnt(4) (2 halves in flight),
// never 0 in the main loop (only the final tile's K1 wait drains).
// MODE 0: GELU -> bf16   MODE 1: +bias -> bf16
// MODE 2: +bias -> fp32 strided into [B,KH,T,V], cols guarded < VOC
// ---------------------------------------------------------------------------

__device__ __forceinline__ void stage_half(const unsigned short* __restrict__ g, int ldK,
                                           unsigned short* l, int wave, int lane) {
#pragma unroll
  for (int r = 0; r < 2; ++r) {
    const int Pb  = r * 8192 + wave * 1024;  // wave-uniform byte base within 16KB half
    const int P   = Pb + lane * 16;          // this lane's landing slot (linear)
    const int row = P >> 6;                  // 64 B per row (32 bf16)
    const int cb  = P & 63;
    async_cp16(g + (size_t)row * ldK + (cb >> 1), l + (Pb >> 1));
  }
}

#define LDSF(buf, off) (*(const bf16x8*)((buf) + (off)))

#define PH_PRE()                                      \
  __builtin_amdgcn_s_barrier();                       \
  asm volatile("s_waitcnt lgkmcnt(0)" ::: "memory"); \
  __builtin_amdgcn_s_setprio(1)

#define PH_POST() __builtin_amdgcn_s_setprio(0)

#define MROW(mi, a, B0, B1, B2, B3)                                                   \
  acc[mi][0] = __builtin_amdgcn_mfma_f32_16x16x32_bf16(a, B0, acc[mi][0], 0, 0, 0);   \
  acc[mi][1] = __builtin_amdgcn_mfma_f32_16x16x32_bf16(a, B1, acc[mi][1], 0, 0, 0);   \
  acc[mi][2] = __builtin_amdgcn_mfma_f32_16x16x32_bf16(a, B2, acc[mi][2], 0, 0, 0);   \
  acc[mi][3] = __builtin_amdgcn_mfma_f32_16x16x32_bf16(a, B3, acc[mi][3], 0, 0, 0);

#define TILE4(KT, CUR, NXT)                                                          \
  {                                                                                  \
    const bool st = ((KT) + 1) < nkt;                                                \
    const int kn = ((KT) + 1) << 6;                                                  \
    bf16x8 af0, af1, af2, af3, b00, b01, b02, b03, b10, b11, b12, b13;               \
    /* phase 1: ks=0, wave-row-half 0 */                                             \
    af0 = LDSF(As[CUR][0], aoff);                                                    \
    af1 = LDSF(As[CUR][0], aoff + 512);                                              \
    af2 = LDSF(As[CUR][0], aoff + 1024);                                             \
    af3 = LDSF(As[CUR][0], aoff + 1536);                                             \
    b00 = LDSF(Bs[CUR][0], boff);                                                    \
    b01 = LDSF(Bs[CUR][0], boff + 512);                                              \
    b02 = LDSF(Bs[CUR][0], boff + 1024);                                             \
    b03 = LDSF(Bs[CUR][0], boff + 1536);                                             \
    if (st) stage_half(gA + kn, Kd, &As[NXT][0][0], wave, lane);                     \
    PH_PRE();                                                                        \
    MROW(0, af0, b00, b01, b02, b03)                                                 \
    MROW(1, af1, b00, b01, b02, b03)                                                 \
    MROW(2, af2, b00, b01, b02, b03)                                                 \
    MROW(3, af3, b00, b01, b02, b03)                                                 \
    PH_POST();                                                                       \
    __builtin_amdgcn_s_barrier();                                                    \
    /* phase 2: ks=0, wave-row-half 1 */                                             \
    af0 = LDSF(As[CUR][0], aoff + 2048);                                             \
    af1 = LDSF(As[CUR][0], aoff + 2560);                                             \
    af2 = LDSF(As[CUR][0], aoff + 3072);                                             \
    af3 = LDSF(As[CUR][0], aoff + 3584);                                             \
    if (st) stage_half(gB + kn, Kd, &Bs[NXT][0][0], wave, lane);                     \
    PH_PRE();                                                                        \
    MROW(4, af0, b00, b01, b02, b03)                                                 \
    MROW(5, af1, b00, b01, b02, b03)                                                 \
    MROW(6, af2, b00, b01, b02, b03)                                                 \
    MROW(7, af3, b00, b01, b02, b03)                                                 \
    PH_POST();                                                                       \
    if (st) { asm volatile("s_waitcnt vmcnt(4)" ::: "memory"); }                     \
    else    { asm volatile("s_waitcnt vmcnt(0)" ::: "memory"); }                     \
    __builtin_amdgcn_s_barrier();                                                    \
    /* phase 3: ks=1, wave-row-half 0 */                                             \
    af0 = LDSF(As[CUR][1], aoff);                                                    \
    af1 = LDSF(As[CUR][1], aoff + 512);                                              \
    af2 = LDSF(As[CUR][1], aoff + 1024);                                             \
    af3 = LDSF(As[CUR][1], aoff + 1536);                                             \
    b10 = LDSF(Bs[CUR][1], boff);                                                    \
    b11 = LDSF(Bs[CUR][1], boff + 512);                                              \
    b12 = LDSF(Bs[CUR][1], boff + 1024);                                             \
    b13 = LDSF(Bs[CUR][1], boff + 1536);                                             \
    if (st) stage_half(gA + kn + 32, Kd, &As[NXT][1][0], wave, lane);                \
    PH_PRE();                                                                        \
    MROW(0, af0, b10, b11, b12, b13)                                                 \
    MROW(1, af1, b10, b11, b12, b13)                                                 \
    MROW(2, af2, b10, b11, b12, b13)                                                 \
    MROW(3, af3, b10, b11, b12, b13)                                                 \
    PH_POST();                                                                       \
    __builtin_amdgcn_s_barrier();                                                    \
    /* phase 4: ks=1, wave-row-half 1 */                                             \
    af0 = LDSF(As[CUR][1], aoff + 2048);                                             \
    af1 = LDSF(As[CUR][1], aoff + 2560);                                             \
    af2 = LDSF(As[CUR][1], aoff + 3072);                                             \
    af3 = LDSF(As[CUR][1], aoff + 3584);                                             \
    if (st) stage_half(gB + kn + 32, Kd, &Bs[NXT][1][0], wave, lane);                \
    PH_PRE();                                                                        \
    MROW(4, af0, b10, b11, b12, b13)                                                 \
    MROW(5, af1, b10, b11, b12, b13)                                                 \
    MROW(6, af2, b10, b11, b12, b13)                                                 \
    MROW(7, af3, b10, b11, b12, b13)                                                 \
    PH_POST();                                                                       \
    if (st) { asm volatile("s_waitcnt vmcnt(4)" ::: "memory"); }                     \
    __builtin_amdgcn_s_barrier();                                                    \
  }

template <int MODE>
__global__ __launch_bounds__(512, 2) void gemm_bt(const unsigned short* __restrict__ A,
                                                  size_t aStrideH,
                                                  const unsigned short* __restrict__ Bt,
                                                  size_t bStrideH,
                                                  const float* __restrict__ bias,
                                                  int biasStrideH,
                                                  unsigned short* __restrict__ ob,
                                                  size_t obStrideH,
                                                  float* __restrict__ of,
                                                  int Kd, int ldo, int khBase) {
  __shared__ __align__(16) unsigned short As[2][2][256 * 32];  // [dbuf][khalf][row*32+k]
  __shared__ __align__(16) unsigned short Bs[2][2][256 * 32];  // 128 KiB total

  // XCD-aware bijective swizzle (all grids here have nwg % 8 == 0):
  // blocks with the same (lin % 8) [same XCD] get consecutive tiles -> L2 reuse.
  const int X = gridDim.x, Y = gridDim.y;
  const int lin = blockIdx.x + X * (blockIdx.y + Y * blockIdx.z);
  const int nwg = X * Y * gridDim.z;
  const int sw  = (lin & 7) * (nwg >> 3) + (lin >> 3);
  const int bx  = sw % X;
  const int t2  = sw / X;
  const int by  = t2 % Y;
  const int kh  = t2 / Y + khBase;

  A    += (size_t)kh * aStrideH;
  Bt   += (size_t)kh * bStrideH;
  bias += (size_t)kh * biasStrideH;
  ob   += (size_t)kh * obStrideH;

  const int tile_m = by * 256;
  const int tile_n = bx * 256;
  const int tid  = threadIdx.x;
  const int wave = tid >> 6;
  const int lane = tid & 63;
  const int wr = wave >> 2;       // 0..1  (M half of tile)
  const int wc = wave & 3;        // 0..3  (N quarter of tile)
  const int al = lane & 15;
  const int kq = lane >> 4;
  const int aoff = (wr * 128 + al) * 32 + kq * 8;  // shorts
  const int boff = (wc * 64 + al) * 32 + kq * 8;

  const unsigned short* gA = A  + (size_t)tile_m * Kd;
  const unsigned short* gB = Bt + (size_t)tile_n * Kd;
  const int nkt = Kd >> 6;  // K-tiles of 64 (16 or 32 here; always even)

  f32x4 acc[8][4];
#pragma unroll
  for (int i = 0; i < 8; i++)
#pragma unroll
    for (int j = 0; j < 4; j++) acc[i][j] = (f32x4){0.f, 0.f, 0.f, 0.f};

  // Prologue: stage tile 0 (A-K0, B-K0, A-K1, B-K1), wait first pair only.
  stage_half(gA,      Kd, &As[0][0][0], wave, lane);
  stage_half(gB,      Kd, &Bs[0][0][0], wave, lane);
  stage_half(gA + 32, Kd, &As[0][1][0], wave, lane);
  stage_half(gB + 32, Kd, &Bs[0][1][0], wave, lane);
  asm volatile("s_waitcnt vmcnt(4)" ::: "memory");
  __builtin_amdgcn_s_barrier();

#pragma unroll 1
  for (int kt = 0; kt < nkt; kt += 2) {
    TILE4(kt, 0, 1);
    TILE4(kt + 1, 1, 0);
  }

  // Epilogue. C/D layout: col = lane&15 (n), row = (lane>>4)*4 + reg (m).
  const int rg = kq * 4;
#pragma unroll
  for (int nj = 0; nj < 4; ++nj) {
    const int gcol = tile_n + wc * 64 + nj * 16 + al;
    float bj = 0.f;
    if (MODE != 2 || gcol < VOC) bj = bias[gcol];
#pragma unroll
    for (int mi = 0; mi < 8; ++mi) {
      const int grow = tile_m + wr * 128 + mi * 16 + rg;
#pragma unroll
      for (int r = 0; r < 4; ++r) {
        float v = acc[mi][nj][r] + bj;
        if (MODE == 0) {
          ob[(size_t)(grow + r) * ldo + gcol] = f2bf(fast_gelu(v));
        } else if (MODE == 1) {
          ob[(size_t)(grow + r) * ldo + gcol] = f2bf(v);
        } else {
          if (gcol < VOC) {
            int m = grow + r;
            int b = m >> 11, t = m & 2047;  // T = 2048
            of[((size_t)(b * KH + kh) * TT + t) * VOC + gcol] = v;
          }
        }
      }
    }
  }
}

// ---------------------------------------------------------------------------
extern "C" void kernel_launch(void* const* d_in, const int* in_sizes, int n_in,
                              void* d_out, int out_size, void* d_ws, size_t ws_size,
                              hipStream_t stream) {
  const float* x        = (const float*)d_in[0];
  const float* ln_scale = (const float*)d_in[1];
  const float* ln_bias  = (const float*)d_in[2];
  const float* W1       = (const float*)d_in[3];
  const float* b1       = (const float*)d_in[4];
  const float* W2       = (const float*)d_in[5];
  const float* b2       = (const float*)d_in[6];
  const float* Wc       = (const float*)d_in[7];
  const float* bc       = (const float*)d_in[8];
  float* out = (float*)d_out;

  char* p = (char*)d_ws;
  auto alloc = [&](size_t bytes) {
    char* r = p;
    p += (bytes + 255) & ~(size_t)255;
    return r;
  };
  unsigned short* xn  = (unsigned short*)alloc((size_t)MM * DM * 2);
  unsigned short* w1t = (unsigned short*)alloc((size_t)KH * HID * DM * 2);   // [k][h][d]
  float*          b1s = (float*)alloc((size_t)KH * HID * 4);
  unsigned short* w2t = (unsigned short*)alloc((size_t)KH * RP * HID * 2);   // [k][r][h]
  unsigned short* wct = (unsigned short*)alloc((size_t)KH * VPAD * RP * 2);  // [k][v][r]

  // Batched path needs per-head activation buffers; fall back if ws is small.
  const size_t fixed = (size_t)(p - (char*)d_ws);
  const size_t needBatched = fixed + ((size_t)KH * MM * HID * 2 + 256) + ((size_t)KH * MM * RP * 2 + 256);
  const bool batched = ws_size >= needBatched;

  unsigned short* hbuf;
  unsigned short* gbuf;
  size_t hStride, gStride;
  if (batched) {
    hbuf = (unsigned short*)alloc((size_t)KH * MM * HID * 2);
    gbuf = (unsigned short*)alloc((size_t)KH * MM * RP * 2);
    hStride = (size_t)MM * HID;
    gStride = (size_t)MM * RP;
  } else {
    hbuf = (unsigned short*)alloc((size_t)MM * HID * 2);
    gbuf = (unsigned short*)alloc((size_t)MM * RP * 2);
    hStride = 0;
    gStride = 0;
  }

  ln_kernel<<<MM, 256, 0, stream>>>(x, xn);
  fold_b1<<<dim3(HID / 64, KH), 256, 0, stream>>>(W1, b1, ln_bias, b1s);
  transpose_conv<<<dim3(HID / 32, DM / 32, KH), 256, 0, stream>>>(W1, w1t, ln_scale, DM, HID, HID, HID * DM);
  transpose_conv<<<dim3(RP / 32, HID / 32, KH), 256, 0, stream>>>(W2, w2t, nullptr, HID, RP, RP, RP * HID);
  transpose_conv<<<dim3(VPAD / 32, RP / 32, KH), 256, 0, stream>>>(Wc, wct, nullptr, RP, VOC, VPAD, VPAD * RP);

  if (batched) {
    gemm_bt<0><<<dim3(HID / 256, MM / 256, KH), 512, 0, stream>>>(
        xn, 0, w1t, (size_t)HID * DM, b1s, HID, hbuf, hStride, nullptr, DM, HID, 0);
    gemm_bt<1><<<dim3(RP / 256, MM / 256, KH), 512, 0, stream>>>(
        hbuf, hStride, w2t, (size_t)RP * HID, b2, RP, gbuf, gStride, nullptr, HID, RP, 0);
    gemm_bt<2><<<dim3(VPAD / 256, MM / 256, KH), 512, 0, stream>>>(
        gbuf, gStride, wct, (size_t)VPAD * RP, bc, VOC, nullptr, 0, out, RP, 0, 0);
  } else {
    for (int kh = 0; kh < KH; kh++) {
      gemm_bt<0><<<dim3(HID / 256, MM / 256, 1), 512, 0, stream>>>(
          xn, 0, w1t + (size_t)kh * HID * DM, 0, b1s + (size_t)kh * HID, 0,
          hbuf, 0, nullptr, DM, HID, kh);
      gemm_bt<1><<<dim3(RP / 256, MM / 256, 1), 512, 0, stream>>>(
          hbuf, 0, w2t + (size_t)kh * RP * HID, 0, b2 + (size_t)kh * RP, 0,
          gbuf, 0, nullptr, HID, RP, kh);
      gemm_bt<2><<<dim3(VPAD / 256, MM / 256, 1), 512, 0, stream>>>(
          gbuf, 0, wct + (size_t)kh * VPAD * RP, 0, bc + (size_t)kh * VOC, 0,
          nullptr, 0, out, RP, 0, kh);
    }
  }
}